// Round 1
// baseline (10701.875 us; speedup 1.0000x reference)
//
#include <hip/hip_runtime.h>
#include <hip/hip_bf16.h>

// Problem sizes (fixed by reference)
#define Bd 128
#define Sd 1024
#define Id 512
#define Hd 512

// Scan decomposition: 8 batch-groups x 8 j-slice blocks
#define NG 8
#define NC 8
#define BB 16   // batches per group
#define JW 64   // H columns per block

typedef __attribute__((ext_vector_type(8))) short short8;   // 8 bf16 (4 VGPRs)
typedef __attribute__((ext_vector_type(4))) float f32x4;

__device__ __forceinline__ unsigned int bf16_rn_bits(float x){
  unsigned int bx = __float_as_uint(x);
  return (bx + 0x7FFFu + ((bx >> 16) & 1u)) >> 16;   // round-to-nearest-even
}

// ---------------------------------------------------------------------------
// K1: xh = inputs @ W_ih + bias_h   (written into d_out, consumed in-place by scan)
// fp32 SGEMM, 128x128 tile, BK=16, 8x8 microtile (split 4+4 to avoid LDS conflicts)
// ---------------------------------------------------------------------------
__global__ __launch_bounds__(256) void k_xh(const float* __restrict__ X,
                                            const float* __restrict__ W,
                                            const float* __restrict__ bias,
                                            float* __restrict__ out)
{
  const int bidm = blockIdx.x >> 2;   // 0..1023 : 128-row tile of BS=131072
  const int bidn = blockIdx.x & 3;    // 0..3    : 128-col tile of H=512
  const int t  = threadIdx.x;
  const int tx = t & 15, ty = t >> 4;

  __shared__ __align__(16) float At[16][132];   // transposed A tile [k][m]
  __shared__ __align__(16) float Bt[16][132];   // B tile [k][n]

  float acc[8][8];
  #pragma unroll
  for (int i = 0; i < 8; ++i)
    #pragma unroll
    for (int j = 0; j < 8; ++j) acc[i][j] = 0.f;

  const float* Xb = X + (size_t)bidm * 128 * Id;
  const float* Wb = W + bidn * 128;

  for (int k0 = 0; k0 < Id; k0 += 16) {
    #pragma unroll
    for (int f = t; f < 512; f += 256) {          // A: 128 rows x 16 k
      int m = f >> 2, c = (f & 3) * 4;
      float4 v = *(const float4*)(Xb + (size_t)m * Id + k0 + c);
      At[c + 0][m] = v.x; At[c + 1][m] = v.y; At[c + 2][m] = v.z; At[c + 3][m] = v.w;
    }
    #pragma unroll
    for (int f = t; f < 512; f += 256) {          // B: 16 k x 128 n
      int kr = f >> 5, nc = (f & 31) * 4;
      *(float4*)&Bt[kr][nc] = *(const float4*)(Wb + (size_t)(k0 + kr) * Hd + nc);
    }
    __syncthreads();
    #pragma unroll
    for (int k = 0; k < 16; ++k) {
      float a[8], b[8];
      *(float4*)(a)     = *(float4*)&At[k][ty * 4];
      *(float4*)(a + 4) = *(float4*)&At[k][64 + ty * 4];
      *(float4*)(b)     = *(float4*)&Bt[k][tx * 4];
      *(float4*)(b + 4) = *(float4*)&Bt[k][64 + tx * 4];
      #pragma unroll
      for (int i = 0; i < 8; ++i)
        #pragma unroll
        for (int j = 0; j < 8; ++j)
          acc[i][j] = fmaf(a[i], b[j], acc[i][j]);
    }
    __syncthreads();
  }

  float bj[8];
  *(float4*)(bj)     = *(const float4*)(bias + bidn * 128 + tx * 4);
  *(float4*)(bj + 4) = *(const float4*)(bias + bidn * 128 + 64 + tx * 4);
  size_t obase = (size_t)bidm * 128 * Hd + bidn * 128;
  #pragma unroll
  for (int i = 0; i < 8; ++i) {
    int m = (i < 4) ? (ty * 4 + i) : (64 + ty * 4 + i - 4);
    float o[8];
    #pragma unroll
    for (int j = 0; j < 8; ++j) o[j] = acc[i][j] + bj[j];
    *(float4*)(out + obase + (size_t)m * Hd + tx * 4)      = *(float4*)(o);
    *(float4*)(out + obase + (size_t)m * Hd + 64 + tx * 4) = *(float4*)(o + 4);
  }
}

// ---------------------------------------------------------------------------
// K1b: xr = inputs @ W_ir + b_r ; xi = inputs @ W_ii + b_i   (one wave per row)
// ---------------------------------------------------------------------------
__global__ __launch_bounds__(256) void k_xri(const float* __restrict__ X,
                                             const float* __restrict__ Wir,
                                             const float* __restrict__ Wii,
                                             const float* __restrict__ br,
                                             const float* __restrict__ bi,
                                             float* __restrict__ xrp,
                                             float* __restrict__ xip)
{
  const int lane = threadIdx.x & 63;
  const int wv   = threadIdx.x >> 6;
  const size_t row = (size_t)blockIdx.x * 4 + wv;
  const float* xp = X + row * Id + lane * 8;
  float4 x0 = *(const float4*)(xp);
  float4 x1 = *(const float4*)(xp + 4);
  float4 r0 = *(const float4*)(Wir + lane * 8);
  float4 r1 = *(const float4*)(Wir + lane * 8 + 4);
  float4 i0 = *(const float4*)(Wii + lane * 8);
  float4 i1 = *(const float4*)(Wii + lane * 8 + 4);
  float sr = x0.x*r0.x + x0.y*r0.y + x0.z*r0.z + x0.w*r0.w
           + x1.x*r1.x + x1.y*r1.y + x1.z*r1.z + x1.w*r1.w;
  float si = x0.x*i0.x + x0.y*i0.y + x0.z*i0.z + x0.w*i0.w
           + x1.x*i1.x + x1.y*i1.y + x1.z*i1.z + x1.w*i1.w;
  #pragma unroll
  for (int o = 32; o; o >>= 1) { sr += __shfl_xor(sr, o, 64); si += __shfl_xor(si, o, 64); }
  if (lane == 0) { xrp[row] = sr + br[0]; xip[row] = si + bi[0]; }
}

// ---------------------------------------------------------------------------
// K2: persistent scan. 64 blocks = 8 batch-groups x 8 j-slices.
//  - W_hh slice resident in VGPRs as bf16 hi/lo MFMA B-fragments (3-term split
//    MFMA == fp32-accurate: hh*Wh + hh*Wl + hl*Wh)
//  - full h (group's 16 batches) in LDS: fp32 + XOR-swizzled bf16 hi/lo
//  - per-step all-to-all h exchange via parity-double-buffered global xbuf +
//    device-scope release/acquire flags (2-deep pipeline => parity is safe)
//  - xh lives in d_out; read slot (b,t) then overwritten with h_t (in-place)
// ---------------------------------------------------------------------------
__global__ __launch_bounds__(256, 1) void k_scan(
    const float* __restrict__ xr, const float* __restrict__ xi,
    const float* __restrict__ Whh, const float* __restrict__ Whr,
    const float* __restrict__ Whi,
    float* __restrict__ hs, float* __restrict__ hlast,
    float* __restrict__ xbuf, int* __restrict__ flags)
{
  const int bid  = blockIdx.x;
  const int g    = bid & 7;        // batch group (round-robin => same XCD per group)
  const int c    = bid >> 3;       // j-slice index 0..7
  const int tid  = threadIdx.x;
  const int lane = tid & 63;
  const int wv   = tid >> 6;
  const int bBase = g * BB;
  const int jBase = c * JW;

  __shared__ __align__(16) float hsm[BB][Hd];              // h_t fp32
  __shared__ __align__(16) unsigned short hhi[BB * Hd];    // h_t bf16 hi (swizzled)
  __shared__ __align__(16) unsigned short hlo[BB * Hd];    // h_t bf16 lo (swizzled)
  __shared__ __align__(16) float whr_s[Hd];
  __shared__ __align__(16) float whi_s[Hd];
  __shared__ float zbuf[BB], rbuf[BB];

  for (int i = tid; i < Hd; i += 256) { whr_s[i] = Whr[i]; whi_s[i] = Whi[i]; }
  for (int i = tid; i < BB * Hd / 4; i += 256) ((float4*)hsm)[i] = make_float4(0, 0, 0, 0);
  for (int i = tid; i < BB * Hd / 2; i += 256) { ((unsigned int*)hhi)[i] = 0u; ((unsigned int*)hlo)[i] = 0u; }

  // ---- preload W_hh B-fragments (one-time, uncoalesced but tiny) ----
  // B-frag layout for mfma_f32_16x16x32_bf16: lane holds B[k=(lane>>4)*8+i][n=lane&15]
  const int n16 = lane & 15, kq = lane >> 4;
  const int jglob = jBase + wv * 16 + n16;
  short8 wfh[16], wfl[16];
  #pragma unroll
  for (int kt = 0; kt < 16; ++kt) {
    short8 ph, pl;
    #pragma unroll
    for (int i = 0; i < 8; ++i) {
      int k = kt * 32 + kq * 8 + i;
      float x = Whh[(size_t)k * Hd + jglob];
      unsigned int hb = bf16_rn_bits(x);
      float hf = __uint_as_float(hb << 16);
      unsigned int lb = bf16_rn_bits(x - hf);
      ph[i] = (short)hb;
      pl[i] = (short)lb;
    }
    wfh[kt] = ph; wfl[kt] = pl;
  }
  __syncthreads();

  const int myflag = g * NC + c;

  for (int t = 0; t < Sd; ++t) {
    // ---------- gates: z = sig(xr + h.Whr), r = sig(xi + h.Whi) ----------
    {
      int b = tid >> 4, l16 = tid & 15;
      float sr = 0.f, si = 0.f;
      #pragma unroll
      for (int kk = 0; kk < 8; ++kk) {
        float4 hv  = *(float4*)&hsm[b][kk * 64 + l16 * 4];
        float4 wr  = *(float4*)&whr_s[kk * 64 + l16 * 4];
        float4 wi2 = *(float4*)&whi_s[kk * 64 + l16 * 4];
        sr += hv.x*wr.x  + hv.y*wr.y  + hv.z*wr.z  + hv.w*wr.w;
        si += hv.x*wi2.x + hv.y*wi2.y + hv.z*wi2.z + hv.w*wi2.w;
      }
      #pragma unroll
      for (int o = 8; o; o >>= 1) { sr += __shfl_xor(sr, o, 64); si += __shfl_xor(si, o, 64); }
      if (l16 == 0) {
        size_t bg = bBase + b;
        zbuf[b] = 1.f / (1.f + __expf(-(xr[bg * Sd + t] + sr)));
        rbuf[b] = 1.f / (1.f + __expf(-(xi[bg * Sd + t] + si)));
      }
    }
    __syncthreads();

    // ---------- xh prefetch (consumed in epilogue; latency hidden by MFMA) ----
    float xhv[4];
    #pragma unroll
    for (int r2 = 0; r2 < 4; ++r2) {
      int m = (lane >> 4) * 4 + r2;
      xhv[r2] = hs[((size_t)(bBase + m) * Sd + t) * Hd + jglob];
    }

    // ---------- v = h @ Whh_slice, 3-term bf16 split (3 indep acc chains) ----
    // A-frag: lane holds A[m=lane&15][k=(lane>>4)*8+i]; LDS XOR-swizzled (G4 fix)
    f32x4 a0 = {0,0,0,0}, a1 = {0,0,0,0}, a2 = {0,0,0,0};
    {
      const int abase = (lane & 15) * 1024 + (lane >> 4) * 16;
      const int sw = (lane & 7) << 4;
      #pragma unroll
      for (int kt = 0; kt < 16; ++kt) {
        int off = (abase + kt * 64) ^ sw;
        short8 ah = *(short8*)((char*)hhi + off);
        short8 al = *(short8*)((char*)hlo + off);
        a0 = __builtin_amdgcn_mfma_f32_16x16x32_bf16(ah, wfh[kt], a0, 0, 0, 0);
        a1 = __builtin_amdgcn_mfma_f32_16x16x32_bf16(ah, wfl[kt], a1, 0, 0, 0);
        a2 = __builtin_amdgcn_mfma_f32_16x16x32_bf16(al, wfh[kt], a2, 0, 0, 0);
      }
    }

    // ---------- epilogue: n = tanh(xh + r*v); h' = z*h + (1-z)*n ----------
    {
      int par = (t + 1) & 1;
      float* xslot = xbuf + ((size_t)g * 2 + par) * BB * Hd;
      #pragma unroll
      for (int r2 = 0; r2 < 4; ++r2) {
        int m = (lane >> 4) * 4 + r2;             // C-layout: col=lane&15, row=(lane>>4)*4+reg
        float v  = a0[r2] + a1[r2] + a2[r2];
        float rr = rbuf[m], zz = zbuf[m];
        float xv = xhv[r2] + rr * v;
        float n  = 1.f - 2.f / (__expf(2.f * xv) + 1.f);   // tanh
        float hnew = zz * hsm[m][jglob] + (1.f - zz) * n;
        hs[((size_t)(bBase + m) * Sd + t) * Hd + jglob] = hnew;
        if (t == Sd - 1) hlast[(size_t)(bBase + m) * Hd + jglob] = hnew;
        xslot[(size_t)m * Hd + jglob] = hnew;
      }
    }
    __syncthreads();                      // all stores drained (vmcnt0) before fence
    if (tid == 0) {
      __threadfence();                    // release: flush XCD L2 -> coherent point
      __hip_atomic_store(&flags[myflag], t + 1, __ATOMIC_RELAXED, __HIP_MEMORY_SCOPE_AGENT);
    }
    if (tid < NC) {
      while (__hip_atomic_load(&flags[g * NC + tid], __ATOMIC_RELAXED, __HIP_MEMORY_SCOPE_AGENT) <= t)
        __builtin_amdgcn_s_sleep(1);
    }
    __syncthreads();
    __threadfence();                      // acquire: invalidate stale L1/L2 lines

    // ---------- assemble h_{t+1} from all 8 slices ----------
    {
      int par = (t + 1) & 1;
      const float* xslot = xbuf + ((size_t)g * 2 + par) * BB * Hd;
      #pragma unroll
      for (int i = 0; i < 8; ++i) {
        int fid = i * 256 + tid;                  // 2048 float4s, coalesced
        float4 hv = *(const float4*)(xslot + (size_t)fid * 4);
        int b = fid >> 7, kc = fid & 127;
        *(float4*)&hsm[b][kc * 4] = hv;
        float hf4[4] = {hv.x, hv.y, hv.z, hv.w};
        unsigned long long ph = 0ull, pl = 0ull;
        #pragma unroll
        for (int j2 = 0; j2 < 4; ++j2) {
          unsigned int hb = bf16_rn_bits(hf4[j2]);
          float hff = __uint_as_float(hb << 16);
          unsigned int lb = bf16_rn_bits(hf4[j2] - hff);
          ph |= (unsigned long long)(hb & 0xFFFFu) << (16 * j2);
          pl |= (unsigned long long)(lb & 0xFFFFu) << (16 * j2);
        }
        int off = (b * 1024 + kc * 8) ^ ((b & 7) << 4);   // same involution as reader
        *(unsigned long long*)((char*)hhi + off) = ph;
        *(unsigned long long*)((char*)hlo + off) = pl;
      }
    }
    __syncthreads();
  }
}

// ---------------------------------------------------------------------------
extern "C" void kernel_launch(void* const* d_in, const int* in_sizes, int n_in,
                              void* d_out, int out_size, void* d_ws, size_t ws_size,
                              hipStream_t stream)
{
  const float* X    = (const float*)d_in[0];
  const float* Wih  = (const float*)d_in[1];
  const float* Whh  = (const float*)d_in[2];
  const float* Wir  = (const float*)d_in[3];
  const float* Whr  = (const float*)d_in[4];
  const float* Wii  = (const float*)d_in[5];
  const float* Whi  = (const float*)d_in[6];
  const float* bh   = (const float*)d_in[7];
  const float* br   = (const float*)d_in[8];
  const float* bi   = (const float*)d_in[9];
  (void)in_sizes; (void)n_in; (void)out_size;

  float* out   = (float*)d_out;
  float* hlast = out + (size_t)Bd * Sd * Hd;

  // ws layout: xr (512KB) | xi (512KB) | xbuf (512KB) | flags (pad)
  char*  ws    = (char*)d_ws;
  float* xr    = (float*)(ws);
  float* xi    = (float*)(ws + (size_t)Bd * Sd * 4);
  float* xbuf  = (float*)(ws + (size_t)Bd * Sd * 8);
  int*   flags = (int*)  (ws + (size_t)Bd * Sd * 8 + (size_t)NG * 2 * BB * Hd * 4);
  (void)ws_size;  // needs ~1.6 MB

  hipMemsetAsync(flags, 0, NG * NC * sizeof(int), stream);
  k_xh  <<<dim3(4096),            dim3(256), 0, stream>>>(X, Wih, bh, out);
  k_xri <<<dim3(Bd * Sd / 4),     dim3(256), 0, stream>>>(X, Wir, Wii, br, bi, xr, xi);
  k_scan<<<dim3(NG * NC),         dim3(256), 0, stream>>>(xr, xi, Whh, Whr, Whi, out, hlast, xbuf, flags);
}